// Round 1
// baseline (302.019 us; speedup 1.0000x reference)
//
#include <hip/hip_runtime.h>
#include <hip/hip_bf16.h>

// Embedding gather: token_ids [8,4096] int32, embedding_matrix [50257,1024] f32
// -> out [8,4096,1024] f32.  Pure memory-bound row copy.

#define DIM 1024
#define F4_PER_ROW (DIM / 4)   // 256

__global__ __launch_bounds__(256) void embed_gather_kernel(
        const int* __restrict__ ids,
        const float* __restrict__ emb,
        float* __restrict__ out,
        int n_tokens) {
    const int tok = blockIdx.x;
    if (tok >= n_tokens) return;
    const int id = ids[tok];  // wave-uniform -> scalar load
    const float4* __restrict__ src =
        reinterpret_cast<const float4*>(emb + (size_t)id * DIM);
    float4* __restrict__ dst =
        reinterpret_cast<float4*>(out + (size_t)tok * DIM);
    // 256 threads x float4 = 1024 floats = one full row per block.
    dst[threadIdx.x] = src[threadIdx.x];
}

extern "C" void kernel_launch(void* const* d_in, const int* in_sizes, int n_in,
                              void* d_out, int out_size, void* d_ws, size_t ws_size,
                              hipStream_t stream) {
    const int*   ids = (const int*)d_in[0];     // 8*4096 token ids
    const float* emb = (const float*)d_in[1];   // 50257*1024 embedding
    float*       out = (float*)d_out;           // 8*4096*1024

    const int n_tokens = in_sizes[0];           // 32768
    dim3 grid(n_tokens);
    dim3 block(256);
    embed_gather_kernel<<<grid, block, 0, stream>>>(ids, emb, out, n_tokens);
}